// Round 4
// baseline (113.464 us; speedup 1.0000x reference)
//
#include <hip/hip_runtime.h>
#include <math.h>

#define NN   96
#define NPOS (96*96)   // 9216
#define BB   32
#define KV   1024
#define KA   2048
#define PTILE 256
#define NPT  (NPOS/PTILE)  // 36

// ---------------- nb: separable DoG convolutions ----------------
__global__ __launch_bounds__(256) void nb_kernel(
    const float* __restrict__ na_v, const float* __restrict__ na_a,
    const float* __restrict__ na_m, float* __restrict__ cpt)
{
    __shared__ float G[96][100];
    __shared__ float act_s[96][100];
    __shared__ float T1t[24][100];
    const int c  = blockIdx.x >> 2;
    const int js = (blockIdx.x & 3) * 24;
    float l, s;
    if      (c == 0) { l =  1.60f; s = 3.5f;  }
    else if (c == 1) { l = -1.23f; s = 6.3f;  }
    else if (c == 2) { l =  1.00f; s = 5.3f;  }
    else if (c == 3) { l = -0.80f; s = 11.8f; }
    else if (c == 4) { l =  3.80f; s = 3.5f;  }
    else             { l = -3.30f; s = 6.2f;  }
    const float s2 = s * s;
    const int f = c >> 1;
    const float* act = (f == 0) ? na_v : (f == 1) ? na_a : na_m;
    const int tid = threadIdx.x;

    for (int idx = tid; idx < 9216; idx += 256) {
        int j = idx / 96, k = idx - j * 96;
        int d = abs(j - k); d = min(d, 96 - d);
        G[j][k]     = __expf(-0.5f * (float)(d * d) * s2);
        act_s[j][k] = act[idx];
    }
    __syncthreads();

    const int hg3 = (tid >> 3) * 3;
    const int jl3 = (tid & 7) * 3;

    float t1[3][3] = {};
    for (int k0 = 0; k0 < 96; k0 += 4) {
        float4 av[3], gv[3];
        #pragma unroll
        for (int r = 0; r < 3; r++) {
            av[r] = *(const float4*)&act_s[hg3 + r][k0];
            gv[r] = *(const float4*)&G[js + jl3 + r][k0];
        }
        #pragma unroll
        for (int hh = 0; hh < 3; hh++)
            #pragma unroll
            for (int jj = 0; jj < 3; jj++)
                t1[hh][jj] += av[hh].x * gv[jj].x + av[hh].y * gv[jj].y
                            + av[hh].z * gv[jj].z + av[hh].w * gv[jj].w;
    }
    #pragma unroll
    for (int hh = 0; hh < 3; hh++)
        #pragma unroll
        for (int jj = 0; jj < 3; jj++)
            T1t[jl3 + jj][hg3 + hh] = t1[hh][jj];
    __syncthreads();

    float o[3][3] = {};
    for (int h0 = 0; h0 < 96; h0 += 4) {
        float4 gv[3], tv[3];
        #pragma unroll
        for (int r = 0; r < 3; r++) {
            gv[r] = *(const float4*)&G[hg3 + r][h0];
            tv[r] = *(const float4*)&T1t[jl3 + r][h0];
        }
        #pragma unroll
        for (int ii = 0; ii < 3; ii++)
            #pragma unroll
            for (int jj = 0; jj < 3; jj++)
                o[ii][jj] += gv[ii].x * tv[jj].x + gv[ii].y * tv[jj].y
                           + gv[ii].z * tv[jj].z + gv[ii].w * tv[jj].w;
    }
    #pragma unroll
    for (int ii = 0; ii < 3; ii++)
        #pragma unroll
        for (int jj = 0; jj < 3; jj++)
            cpt[c * NPOS + (hg3 + ii) * 96 + (js + jl3 + jj)] = l * o[ii][jj];
}

// ---------------- ext GEMMs: C[b,p] = sum_k src[b,k] * rf[p,k] ----------------
// Thread = 1 position x 32 batch accumulators. vid chunk in LDS, read as
// broadcast float4 (all lanes same address -> conflict-free, proven r1).
// rf streamed per-lane with an explicit 4-group-deep prefetch pipeline.
// kch=128 -> 864 blocks -> ~3.4 blocks/CU (fixes r1's 1.7 blocks/CU).
#define EXT_PROCESS(G_, RA_, RB_)                                          \
    {                                                                      \
        const float* Ak_ = &A[((G_) << 3) * 32];                           \
        float ks_[8] = {RA_.x, RA_.y, RA_.z, RA_.w,                        \
                        RB_.x, RB_.y, RB_.z, RB_.w};                       \
        _Pragma("unroll")                                                  \
        for (int j_ = 0; j_ < 8; ++j_) {                                   \
            const float4* row_ = (const float4*)&Ak_[j_ * 32];             \
            const float bk_ = ks_[j_];                                     \
            _Pragma("unroll")                                              \
            for (int q_ = 0; q_ < 8; ++q_) {                               \
                float4 av_ = row_[q_];                                     \
                acc[q_ * 4 + 0] = fmaf(av_.x, bk_, acc[q_ * 4 + 0]);       \
                acc[q_ * 4 + 1] = fmaf(av_.y, bk_, acc[q_ * 4 + 1]);       \
                acc[q_ * 4 + 2] = fmaf(av_.z, bk_, acc[q_ * 4 + 2]);       \
                acc[q_ * 4 + 3] = fmaf(av_.w, bk_, acc[q_ * 4 + 3]);       \
            }                                                              \
        }                                                                  \
    }

__global__ __launch_bounds__(256, 4) void ext_kernel(
    const float* __restrict__ video, const float* __restrict__ audio,
    const float* __restrict__ rf_v, const float* __restrict__ rf_a,
    float* __restrict__ ws, int kch, int nblk_v, int parta_off)
{
    extern __shared__ float A[];   // [kch][32]
    const int bid = blockIdx.x;
    const float* src; const float* rf; float* part; int K;
    int chunk, ptile;
    if (bid < nblk_v) {
        chunk = bid / NPT; ptile = bid - chunk * NPT;
        src = video; rf = rf_v; K = KV;
        part = ws + (size_t)chunk * (BB * NPOS);
    } else {
        int idx = bid - nblk_v;
        chunk = idx / NPT; ptile = idx - chunk * NPT;
        src = audio; rf = rf_a; K = KA;
        part = ws + parta_off + (size_t)chunk * (BB * NPOS);
    }
    const int kbase = chunk * kch;
    const int tid = threadIdx.x;

    // stage A[k][b]: b = tid&31 -> scalar LDS writes hit 32 distinct banks
    // (2 lanes/bank = free). Global float4 reads per lane (vid is L2-hot).
    {
        const int b   = tid & 31;
        const int kpt = kch >> 3;               // 16 or 32
        const int k0  = (tid >> 5) * kpt;
        const float* sp = src + (size_t)b * K + kbase + k0;
        for (int u = 0; u < kpt; u += 4) {
            float4 v = *(const float4*)&sp[u];
            A[(k0 + u + 0) * 32 + b] = v.x;
            A[(k0 + u + 1) * 32 + b] = v.y;
            A[(k0 + u + 2) * 32 + b] = v.z;
            A[(k0 + u + 3) * 32 + b] = v.w;
        }
    }
    __syncthreads();

    const int p = ptile * PTILE + tid;
    const float4* bp = (const float4*)(rf + (size_t)p * K + kbase);
    float acc[32];
    #pragma unroll
    for (int b = 0; b < 32; b++) acc[b] = 0.f;

    const int ngr = kch >> 3;                   // 16 or 32 groups of 8 k
    // 4-deep explicit pipeline, named buffers (no dynamic reg indexing)
    float4 b0a = bp[0], b0b = bp[1];
    float4 b1a = bp[2], b1b = bp[3];
    float4 b2a = bp[4], b2b = bp[5];
    float4 b3a = bp[6], b3b = bp[7];

    for (int g4 = 0; g4 < ngr; g4 += 4) {
        int gn;
        EXT_PROCESS(g4 + 0, b0a, b0b);
        gn = (g4 + 4 < ngr) ? g4 + 4 : ngr - 1;
        b0a = bp[2 * gn]; b0b = bp[2 * gn + 1];
        EXT_PROCESS(g4 + 1, b1a, b1b);
        gn = (g4 + 5 < ngr) ? g4 + 5 : ngr - 1;
        b1a = bp[2 * gn]; b1b = bp[2 * gn + 1];
        EXT_PROCESS(g4 + 2, b2a, b2b);
        gn = (g4 + 6 < ngr) ? g4 + 6 : ngr - 1;
        b2a = bp[2 * gn]; b2b = bp[2 * gn + 1];
        EXT_PROCESS(g4 + 3, b3a, b3b);
        gn = (g4 + 7 < ngr) ? g4 + 7 : ngr - 1;
        b3a = bp[2 * gn]; b3b = bp[2 * gn + 1];
    }

    #pragma unroll
    for (int b = 0; b < 32; b++) part[(size_t)b * NPOS + p] = acc[b];
}

// ---------------- combine: reduce partials + sigmoid dynamics ----------------
__global__ __launch_bounds__(256) void combine_kernel(
    const float* __restrict__ na_v, const float* __restrict__ na_a,
    const float* __restrict__ na_m, const float* __restrict__ ws,
    float* __restrict__ out, int nchv, int ncha, int parta_off, int cpt_off)
{
    const int npq = NPOS >> 2;
    const int t = blockIdx.x * 256 + threadIdx.x;
    if (t >= BB * npq) return;
    const int b  = t / npq;
    const int p0 = (t - b * npq) << 2;

    float4 ev = {0.f, 0.f, 0.f, 0.f}, ea = {0.f, 0.f, 0.f, 0.f};
    for (int c = 0; c < nchv; c++) {
        float4 x = *(const float4*)&ws[(size_t)c * (BB * NPOS) + (size_t)b * NPOS + p0];
        ev.x += x.x; ev.y += x.y; ev.z += x.z; ev.w += x.w;
    }
    for (int c = 0; c < ncha; c++) {
        float4 x = *(const float4*)&ws[(size_t)parta_off + (size_t)c * (BB * NPOS) + (size_t)b * NPOS + p0];
        ea.x += x.x; ea.y += x.y; ea.z += x.z; ea.w += x.w;
    }
    const float* cpt = ws + cpt_off;
    float4 q0 = *(const float4*)&cpt[0 * NPOS + p0];
    float4 q1 = *(const float4*)&cpt[1 * NPOS + p0];
    float4 q2 = *(const float4*)&cpt[2 * NPOS + p0];
    float4 q3 = *(const float4*)&cpt[3 * NPOS + p0];
    float4 q4 = *(const float4*)&cpt[4 * NPOS + p0];
    float4 q5 = *(const float4*)&cpt[5 * NPOS + p0];
    float4 nv = *(const float4*)&na_v[p0];
    float4 na = *(const float4*)&na_a[p0];
    float4 nm = *(const float4*)&na_m[p0];

    float evs[4] = {ev.x, ev.y, ev.z, ev.w};
    float eas[4] = {ea.x, ea.y, ea.z, ea.w};
    float nbv[4] = {q0.x + q1.x, q0.y + q1.y, q0.z + q1.z, q0.w + q1.w};
    float nba[4] = {q2.x + q3.x, q2.y + q3.y, q2.z + q3.z, q2.w + q3.w};
    float nbm[4] = {q4.x + q5.x, q4.y + q5.y, q4.z + q5.z, q4.w + q5.w};
    float nvs[4] = {nv.x, nv.y, nv.z, nv.w};
    float nas[4] = {na.x, na.y, na.z, na.w};
    float nms[4] = {nm.x, nm.y, nm.z, nm.w};

    float4 o;
    float* os = (float*)&o;
    #pragma unroll
    for (int u = 0; u < 4; u++) {
        const float xv = (evs[u] + nbv[u] - 3.0f + nms[u]) * 0.3f;
        const float nav_new = nvs[u] * (2.f / 3.f) + (1.f / 3.f) / (1.f + __expf(-xv));
        const float xa = (eas[u] + nba[u] - 3.0f + nms[u]) * 0.3f;
        const float naa_new = nas[u] * (2.f / 3.f) + (1.f / 3.f) / (1.f + __expf(-xa));
        const float xm = (7.0f * nav_new + 3.0f * naa_new + nbm[u] - 3.0f) * 0.3f;
        os[u] = nms[u] * (2.f / 3.f) + (1.f / 3.f) / (1.f + __expf(-xm));
    }
    *(float4*)&out[(size_t)b * NPOS + p0] = o;
}

extern "C" void kernel_launch(void* const* d_in, const int* in_sizes, int n_in,
                              void* d_out, int out_size, void* d_ws, size_t ws_size,
                              hipStream_t stream) {
    const float* video = (const float*)d_in[0];
    const float* audio = (const float*)d_in[1];
    const float* rf_v  = (const float*)d_in[2];
    const float* rf_a  = (const float*)d_in[3];
    const float* na_v  = (const float*)d_in[4];
    const float* na_a  = (const float*)d_in[5];
    const float* na_m  = (const float*)d_in[6];
    float* ws  = (float*)d_ws;
    float* out = (float*)d_out;

    int kch, nchv, ncha;
    const size_t need128 = ((size_t)24 * BB * NPOS + 6 * NPOS) * sizeof(float);
    if (ws_size >= need128) { kch = 128; nchv = 8; ncha = 16; }
    else                    { kch = 256; nchv = 4; ncha = 8;  }
    const int parta_off = nchv * BB * NPOS;
    const int cpt_off   = parta_off + ncha * BB * NPOS;

    nb_kernel<<<24, 256, 0, stream>>>(na_v, na_a, na_m, ws + cpt_off);
    ext_kernel<<<(nchv + ncha) * NPT, 256, kch * 32 * 4, stream>>>(
        video, audio, rf_v, rf_a, ws, kch, nchv * NPT, parta_off);
    combine_kernel<<<(BB * NPOS / 4 + 255) / 256, 256, 0, stream>>>(
        na_v, na_a, na_m, ws, out, nchv, ncha, parta_off, cpt_off);
}

// Round 5
// 60.216 us; speedup vs baseline: 1.8843x; 1.8843x over previous
//
#include <hip/hip_runtime.h>
#include <math.h>

#define NN   96
#define NPOS (96*96)   // 9216
#define BB   32
#define KV   1024
#define KA   2048
#define PTILE 256
#define NPT  (NPOS/PTILE)  // 36

// ---------------- nb (separable DoG) + vid/aud transpose, merged ----------------
// blocks 0..23: nb component c = bid>>2, j-stripe (bid&3)*24
// blocks 24..71: transpose video/audio to [k][32] layout (into d_out scratch)
__global__ __launch_bounds__(256) void nbT_kernel(
    const float* __restrict__ na_v, const float* __restrict__ na_a,
    const float* __restrict__ na_m, const float* __restrict__ video,
    const float* __restrict__ audio, float* __restrict__ cpt,
    float* __restrict__ vT, float* __restrict__ aT)
{
    __shared__ float G[96][100];
    __shared__ float act_s[96][100];
    __shared__ float T1t[24][100];

    if (blockIdx.x >= 24) {
        const int t0 = (blockIdx.x - 24) * 256 + threadIdx.x;
        for (int e = t0; e < 32 * KV; e += 48 * 256)
            vT[e] = video[(size_t)(e & 31) * KV + (e >> 5)];
        for (int e = t0; e < 32 * KA; e += 48 * 256)
            aT[e] = audio[(size_t)(e & 31) * KA + (e >> 5)];
        return;
    }

    const int c  = blockIdx.x >> 2;
    const int js = (blockIdx.x & 3) * 24;
    float l, s;
    if      (c == 0) { l =  1.60f; s = 3.5f;  }
    else if (c == 1) { l = -1.23f; s = 6.3f;  }
    else if (c == 2) { l =  1.00f; s = 5.3f;  }
    else if (c == 3) { l = -0.80f; s = 11.8f; }
    else if (c == 4) { l =  3.80f; s = 3.5f;  }
    else             { l = -3.30f; s = 6.2f;  }
    const float s2 = s * s;
    const int f = c >> 1;
    const float* act = (f == 0) ? na_v : (f == 1) ? na_a : na_m;
    const int tid = threadIdx.x;

    for (int idx = tid; idx < 9216; idx += 256) {
        int j = idx / 96, k = idx - j * 96;
        int d = abs(j - k); d = min(d, 96 - d);
        G[j][k]     = __expf(-0.5f * (float)(d * d) * s2);
        act_s[j][k] = act[idx];
    }
    __syncthreads();

    const int hg3 = (tid >> 3) * 3;
    const int jl3 = (tid & 7) * 3;

    float t1[3][3] = {};
    for (int k0 = 0; k0 < 96; k0 += 4) {
        float4 av[3], gv[3];
        #pragma unroll
        for (int r = 0; r < 3; r++) {
            av[r] = *(const float4*)&act_s[hg3 + r][k0];
            gv[r] = *(const float4*)&G[js + jl3 + r][k0];
        }
        #pragma unroll
        for (int hh = 0; hh < 3; hh++)
            #pragma unroll
            for (int jj = 0; jj < 3; jj++)
                t1[hh][jj] += av[hh].x * gv[jj].x + av[hh].y * gv[jj].y
                            + av[hh].z * gv[jj].z + av[hh].w * gv[jj].w;
    }
    #pragma unroll
    for (int hh = 0; hh < 3; hh++)
        #pragma unroll
        for (int jj = 0; jj < 3; jj++)
            T1t[jl3 + jj][hg3 + hh] = t1[hh][jj];
    __syncthreads();

    float o[3][3] = {};
    for (int h0 = 0; h0 < 96; h0 += 4) {
        float4 gv[3], tv[3];
        #pragma unroll
        for (int r = 0; r < 3; r++) {
            gv[r] = *(const float4*)&G[hg3 + r][h0];
            tv[r] = *(const float4*)&T1t[jl3 + r][h0];
        }
        #pragma unroll
        for (int ii = 0; ii < 3; ii++)
            #pragma unroll
            for (int jj = 0; jj < 3; jj++)
                o[ii][jj] += gv[ii].x * tv[jj].x + gv[ii].y * tv[jj].y
                           + gv[ii].z * tv[jj].z + gv[ii].w * tv[jj].w;
    }
    #pragma unroll
    for (int ii = 0; ii < 3; ii++)
        #pragma unroll
        for (int jj = 0; jj < 3; jj++)
            cpt[c * NPOS + (hg3 + ii) * 96 + (js + jl3 + jj)] = l * o[ii][jj];
}

// ---------------- ext GEMMs: C[b,p] = sum_k srcT[k,b] * rf[p,k] ----------------
// No LDS, no barriers. srcT[k][32] is wave-uniform -> compiler emits s_load;
// FMA reads it as the SGPR operand (v_fma v,s,v legal: 1 SGPR/instr).
// rf streamed per-lane, 16-k register block + 1-block prefetch (16 VGPR).
__global__ __launch_bounds__(256) void ext_kernel(
    const float* __restrict__ rf_v, const float* __restrict__ rf_a,
    const float* __restrict__ vT, const float* __restrict__ aT,
    float* __restrict__ ws, int kch, int nblk_v, int parta_off)
{
    const int bid = blockIdx.x;
    const float* srcT; const float* rf; float* part; int K;
    int chunk, ptile;
    if (bid < nblk_v) {
        chunk = bid / NPT; ptile = bid - chunk * NPT;
        srcT = vT; rf = rf_v; K = KV;
        part = ws + (size_t)chunk * (BB * NPOS);
    } else {
        int idx = bid - nblk_v;
        chunk = idx / NPT; ptile = idx - chunk * NPT;
        srcT = aT; rf = rf_a; K = KA;
        part = ws + parta_off + (size_t)chunk * (BB * NPOS);
    }
    const int kbase = chunk * kch;
    const int p = ptile * PTILE + threadIdx.x;
    const float4* rp = (const float4*)(rf + (size_t)p * K + kbase);
    const float* vt = srcT + (size_t)kbase * BB;

    float acc[BB];
    #pragma unroll
    for (int b = 0; b < BB; ++b) acc[b] = 0.f;

    const int nb16 = kch >> 4;   // 16-k blocks (8 @ kch=128)
    float4 c0 = rp[0], c1 = rp[1], c2 = rp[2], c3 = rp[3];
    for (int blk = 0; blk < nb16; ++blk) {
        const int nxt = (blk + 1 < nb16) ? blk + 1 : blk;
        float4 n0 = rp[4 * nxt + 0], n1 = rp[4 * nxt + 1];
        float4 n2 = rp[4 * nxt + 2], n3 = rp[4 * nxt + 3];
        const float* vk = vt + (blk << 4) * BB;
        const float ks[16] = {c0.x, c0.y, c0.z, c0.w, c1.x, c1.y, c1.z, c1.w,
                              c2.x, c2.y, c2.z, c2.w, c3.x, c3.y, c3.z, c3.w};
        #pragma unroll
        for (int kk = 0; kk < 16; ++kk) {
            const float bk = ks[kk];           // per-lane rf value (VGPR)
            const float* vr = vk + kk * BB;    // uniform row -> SGPRs
            #pragma unroll
            for (int b = 0; b < BB; ++b)
                acc[b] = fmaf(vr[b], bk, acc[b]);
        }
        c0 = n0; c1 = n1; c2 = n2; c3 = n3;
    }

    #pragma unroll
    for (int b = 0; b < BB; ++b)
        part[(size_t)b * NPOS + p] = acc[b];
}

// ---------------- combine: reduce partials + sigmoid dynamics ----------------
__global__ __launch_bounds__(256) void combine_kernel(
    const float* __restrict__ na_v, const float* __restrict__ na_a,
    const float* __restrict__ na_m, const float* __restrict__ ws,
    float* __restrict__ out, int nchv, int ncha, int parta_off, int cpt_off)
{
    const int npq = NPOS >> 2;
    const int t = blockIdx.x * 256 + threadIdx.x;
    if (t >= BB * npq) return;
    const int b  = t / npq;
    const int p0 = (t - b * npq) << 2;

    float4 ev = {0.f, 0.f, 0.f, 0.f}, ea = {0.f, 0.f, 0.f, 0.f};
    for (int c = 0; c < nchv; c++) {
        float4 x = *(const float4*)&ws[(size_t)c * (BB * NPOS) + (size_t)b * NPOS + p0];
        ev.x += x.x; ev.y += x.y; ev.z += x.z; ev.w += x.w;
    }
    for (int c = 0; c < ncha; c++) {
        float4 x = *(const float4*)&ws[(size_t)parta_off + (size_t)c * (BB * NPOS) + (size_t)b * NPOS + p0];
        ea.x += x.x; ea.y += x.y; ea.z += x.z; ea.w += x.w;
    }
    const float* cpt = ws + cpt_off;
    float4 q0 = *(const float4*)&cpt[0 * NPOS + p0];
    float4 q1 = *(const float4*)&cpt[1 * NPOS + p0];
    float4 q2 = *(const float4*)&cpt[2 * NPOS + p0];
    float4 q3 = *(const float4*)&cpt[3 * NPOS + p0];
    float4 q4 = *(const float4*)&cpt[4 * NPOS + p0];
    float4 q5 = *(const float4*)&cpt[5 * NPOS + p0];
    float4 nv = *(const float4*)&na_v[p0];
    float4 na = *(const float4*)&na_a[p0];
    float4 nm = *(const float4*)&na_m[p0];

    float evs[4] = {ev.x, ev.y, ev.z, ev.w};
    float eas[4] = {ea.x, ea.y, ea.z, ea.w};
    float nbv[4] = {q0.x + q1.x, q0.y + q1.y, q0.z + q1.z, q0.w + q1.w};
    float nba[4] = {q2.x + q3.x, q2.y + q3.y, q2.z + q3.z, q2.w + q3.w};
    float nbm[4] = {q4.x + q5.x, q4.y + q5.y, q4.z + q5.z, q4.w + q5.w};
    float nvs[4] = {nv.x, nv.y, nv.z, nv.w};
    float nas[4] = {na.x, na.y, na.z, na.w};
    float nms[4] = {nm.x, nm.y, nm.z, nm.w};

    float4 o;
    float* os = (float*)&o;
    #pragma unroll
    for (int u = 0; u < 4; u++) {
        const float xv = (evs[u] + nbv[u] - 3.0f + nms[u]) * 0.3f;
        const float nav_new = nvs[u] * (2.f / 3.f) + (1.f / 3.f) / (1.f + __expf(-xv));
        const float xa = (eas[u] + nba[u] - 3.0f + nms[u]) * 0.3f;
        const float naa_new = nas[u] * (2.f / 3.f) + (1.f / 3.f) / (1.f + __expf(-xa));
        const float xm = (7.0f * nav_new + 3.0f * naa_new + nbm[u] - 3.0f) * 0.3f;
        os[u] = nms[u] * (2.f / 3.f) + (1.f / 3.f) / (1.f + __expf(-xm));
    }
    *(float4*)&out[(size_t)b * NPOS + p0] = o;
}

extern "C" void kernel_launch(void* const* d_in, const int* in_sizes, int n_in,
                              void* d_out, int out_size, void* d_ws, size_t ws_size,
                              hipStream_t stream) {
    const float* video = (const float*)d_in[0];
    const float* audio = (const float*)d_in[1];
    const float* rf_v  = (const float*)d_in[2];
    const float* rf_a  = (const float*)d_in[3];
    const float* na_v  = (const float*)d_in[4];
    const float* na_a  = (const float*)d_in[5];
    const float* na_m  = (const float*)d_in[6];
    float* ws  = (float*)d_ws;
    float* out = (float*)d_out;

    int kch, nchv, ncha;
    const size_t need128 = ((size_t)24 * BB * NPOS + 6 * NPOS) * sizeof(float);
    if (ws_size >= need128) { kch = 128; nchv = 8; ncha = 16; }
    else                    { kch = 256; nchv = 4; ncha = 8;  }
    const int parta_off = nchv * BB * NPOS;
    const int cpt_off   = parta_off + ncha * BB * NPOS;

    // d_out doubles as scratch for the transposed vid/aud (384 KB < 1.18 MB);
    // combine_kernel fully overwrites d_out afterwards.
    float* vT = out;
    float* aT = out + 32 * KV;

    nbT_kernel<<<24 + 48, 256, 0, stream>>>(na_v, na_a, na_m, video, audio,
                                            ws + cpt_off, vT, aT);
    ext_kernel<<<(nchv + ncha) * NPT, 256, 0, stream>>>(
        rf_v, rf_a, vT, aT, ws, kch, nchv * NPT, parta_off);
    combine_kernel<<<(BB * NPOS / 4 + 255) / 256, 256, 0, stream>>>(
        na_v, na_a, na_m, ws, out, nchv, ncha, parta_off, cpt_off);
}

// Round 6
// 41.306 us; speedup vs baseline: 2.7469x; 1.4578x over previous
//
#include <hip/hip_runtime.h>
#include <math.h>

#define NN   96
#define NPOS (96*96)   // 9216
#define BB   32
#define KV   1024
#define KA   2048
#define KCH  512
#define NCHV (KV/KCH)        // 2
#define NCHA (KA/KCH)        // 4
#define PT16 (NPOS/16)       // 576 pos-tiles per k-chunk
#define NBLK_V (NCHV*PT16)   // 1152
#define NBLK_A (NCHA*PT16)   // 2304

// ws layout (float offsets)
#define PARTV_OFF 0
#define PARTA_OFF (NCHV*BB*NPOS)               // 589824
#define CPT_OFF   (PARTA_OFF + NCHA*BB*NPOS)   // 1769472
#define AFV_OFF   (CPT_OFF + 6*NPOS)           // 1824768 (16B aligned)
#define AFV_SLOTS ((KV/32)*2*64)               // 4096 slots of 16B
#define AFA_OFF   (AFV_OFF + AFV_SLOTS*4)
#define AFA_SLOTS ((KA/32)*2*64)               // 8192
// total ws = 7.5 MB (previous rounds proved >= 28.6 MB available)

typedef __bf16 bf16x8 __attribute__((ext_vector_type(8)));
typedef float  f32x4  __attribute__((ext_vector_type(4)));

// ---------------- nb (separable DoG) + vid/aud -> bf16 A-fragment pack ----------------
// blocks 0..23: nb component c = bid>>2, j-stripe (bid&3)*24
// blocks 24..71: pack video/audio into MFMA A-fragment layout (bf16) in ws
__global__ __launch_bounds__(256) void nbT_kernel(
    const float* __restrict__ na_v, const float* __restrict__ na_a,
    const float* __restrict__ na_m, const float* __restrict__ video,
    const float* __restrict__ audio, float* __restrict__ ws)
{
    __shared__ float G[96][100];
    __shared__ float act_s[96][100];
    __shared__ float T1t[24][100];

    if (blockIdx.x >= 24) {
        // A-fragment pack: slot e -> lane l, batch-half hb, k-step sg.
        // A[16x32] lane layout: row = l&15, k = (l>>4)*8 + j  (guide-verified)
        const int e = (blockIdx.x - 24) * 256 + threadIdx.x;   // 0..12287
        const float* src; bf16x8* dst; int K, el;
        if (e < AFV_SLOTS) { src = video; K = KV; dst = (bf16x8*)(ws + AFV_OFF); el = e; }
        else               { src = audio; K = KA; dst = (bf16x8*)(ws + AFA_OFF); el = e - AFV_SLOTS; }
        const int l  = el & 63;
        const int hb = (el >> 6) & 1;
        const int sg = el >> 7;
        const int b  = hb * 16 + (l & 15);
        const int k0 = sg * 32 + ((l >> 4) << 3);
        const float4 f0 = *(const float4*)&src[(size_t)b * K + k0];
        const float4 f1 = *(const float4*)&src[(size_t)b * K + k0 + 4];
        bf16x8 v;
        v[0] = (__bf16)f0.x; v[1] = (__bf16)f0.y; v[2] = (__bf16)f0.z; v[3] = (__bf16)f0.w;
        v[4] = (__bf16)f1.x; v[5] = (__bf16)f1.y; v[6] = (__bf16)f1.z; v[7] = (__bf16)f1.w;
        dst[el] = v;
        return;
    }

    const int c  = blockIdx.x >> 2;
    const int js = (blockIdx.x & 3) * 24;
    float l, s;
    if      (c == 0) { l =  1.60f; s = 3.5f;  }
    else if (c == 1) { l = -1.23f; s = 6.3f;  }
    else if (c == 2) { l =  1.00f; s = 5.3f;  }
    else if (c == 3) { l = -0.80f; s = 11.8f; }
    else if (c == 4) { l =  3.80f; s = 3.5f;  }
    else             { l = -3.30f; s = 6.2f;  }
    const float s2 = s * s;
    const int f = c >> 1;
    const float* act = (f == 0) ? na_v : (f == 1) ? na_a : na_m;
    const int tid = threadIdx.x;
    float* cpt = ws + CPT_OFF;

    for (int idx = tid; idx < 9216; idx += 256) {
        int j = idx / 96, k = idx - j * 96;
        int d = abs(j - k); d = min(d, 96 - d);
        G[j][k]     = __expf(-0.5f * (float)(d * d) * s2);
        act_s[j][k] = act[idx];
    }
    __syncthreads();

    const int hg3 = (tid >> 3) * 3;
    const int jl3 = (tid & 7) * 3;

    float t1[3][3] = {};
    for (int k0 = 0; k0 < 96; k0 += 4) {
        float4 av[3], gv[3];
        #pragma unroll
        for (int r = 0; r < 3; r++) {
            av[r] = *(const float4*)&act_s[hg3 + r][k0];
            gv[r] = *(const float4*)&G[js + jl3 + r][k0];
        }
        #pragma unroll
        for (int hh = 0; hh < 3; hh++)
            #pragma unroll
            for (int jj = 0; jj < 3; jj++)
                t1[hh][jj] += av[hh].x * gv[jj].x + av[hh].y * gv[jj].y
                            + av[hh].z * gv[jj].z + av[hh].w * gv[jj].w;
    }
    #pragma unroll
    for (int hh = 0; hh < 3; hh++)
        #pragma unroll
        for (int jj = 0; jj < 3; jj++)
            T1t[jl3 + jj][hg3 + hh] = t1[hh][jj];
    __syncthreads();

    float o[3][3] = {};
    for (int h0 = 0; h0 < 96; h0 += 4) {
        float4 gv[3], tv[3];
        #pragma unroll
        for (int r = 0; r < 3; r++) {
            gv[r] = *(const float4*)&G[hg3 + r][h0];
            tv[r] = *(const float4*)&T1t[jl3 + r][h0];
        }
        #pragma unroll
        for (int ii = 0; ii < 3; ii++)
            #pragma unroll
            for (int jj = 0; jj < 3; jj++)
                o[ii][jj] += gv[ii].x * tv[jj].x + gv[ii].y * tv[jj].y
                           + gv[ii].z * tv[jj].z + gv[ii].w * tv[jj].w;
    }
    #pragma unroll
    for (int ii = 0; ii < 3; ii++)
        #pragma unroll
        for (int jj = 0; jj < 3; jj++)
            cpt[c * NPOS + (hg3 + ii) * 96 + (js + jl3 + jj)] = l * o[ii][jj];
}

// ---------------- ext GEMM via MFMA: ext[b,p] = sum_k vid[b,k]*rf[p,k] ----------------
// 1 wave/block, 16 positions/wave, kch=512. D = A(vid 16x32) * B(rf^T 32x16).
// A from prepacked bf16 fragments (L2-hot, coalesced); B = rf rows streamed
// fp32 (each lane 32B contiguous), cvt to bf16 in-flight. No LDS, no barriers.
__global__ __launch_bounds__(64) void ext_mfma(
    const float* __restrict__ rf_v, const float* __restrict__ rf_a,
    float* __restrict__ ws)
{
    const int bid = blockIdx.x;
    const float* rf; const bf16x8* af; float* part; int K;
    int chunk, pt;
    if (bid < NBLK_V) {
        chunk = bid / PT16; pt = bid - chunk * PT16;
        rf = rf_v; K = KV;
        af = (const bf16x8*)(ws + AFV_OFF);
        part = ws + PARTV_OFF + (size_t)chunk * (BB * NPOS);
    } else {
        const int idx = bid - NBLK_V;
        chunk = idx / PT16; pt = idx - chunk * PT16;
        rf = rf_a; K = KA;
        af = (const bf16x8*)(ws + AFA_OFF);
        part = ws + PARTA_OFF + (size_t)chunk * (BB * NPOS);
    }
    const int kbase = chunk * KCH;
    const int l  = threadIdx.x;
    const int p0 = pt * 16;
    const int prow = p0 + (l & 15);
    const int koff = (l >> 4) * 8;
    const float4* bp = (const float4*)(rf + (size_t)prow * K + kbase + koff);
    const bf16x8* ap = af + (kbase >> 5) * 128 + l;

    f32x4 acc0 = {0.f, 0.f, 0.f, 0.f};
    f32x4 acc1 = {0.f, 0.f, 0.f, 0.f};

    #pragma unroll 4
    for (int st = 0; st < KCH / 32; ++st) {
        bf16x8 a0 = ap[st * 128];        // batches 0..15
        bf16x8 a1 = ap[st * 128 + 64];   // batches 16..31
        float4 f0 = bp[st * 8];
        float4 f1 = bp[st * 8 + 1];
        bf16x8 bv;
        bv[0] = (__bf16)f0.x; bv[1] = (__bf16)f0.y; bv[2] = (__bf16)f0.z; bv[3] = (__bf16)f0.w;
        bv[4] = (__bf16)f1.x; bv[5] = (__bf16)f1.y; bv[6] = (__bf16)f1.z; bv[7] = (__bf16)f1.w;
        acc0 = __builtin_amdgcn_mfma_f32_16x16x32_bf16(a0, bv, acc0, 0, 0, 0);
        acc1 = __builtin_amdgcn_mfma_f32_16x16x32_bf16(a1, bv, acc1, 0, 0, 0);
    }

    // C/D: col(pos) = lane&15, row(batch) = (lane>>4)*4 + reg  (guide-verified)
    const int pcol  = p0 + (l & 15);
    const int brow0 = (l >> 4) * 4;
    #pragma unroll
    for (int r = 0; r < 4; ++r) {
        part[(size_t)(brow0 + r) * NPOS + pcol]        = acc0[r];
        part[(size_t)(16 + brow0 + r) * NPOS + pcol]   = acc1[r];
    }
}

// ---------------- combine: reduce partials + sigmoid dynamics ----------------
__global__ __launch_bounds__(256) void combine_kernel(
    const float* __restrict__ na_v, const float* __restrict__ na_a,
    const float* __restrict__ na_m, const float* __restrict__ ws,
    float* __restrict__ out)
{
    const int npq = NPOS >> 2;
    const int t = blockIdx.x * 256 + threadIdx.x;
    if (t >= BB * npq) return;
    const int b  = t / npq;
    const int p0 = (t - b * npq) << 2;

    float4 ev = {0.f, 0.f, 0.f, 0.f}, ea = {0.f, 0.f, 0.f, 0.f};
    #pragma unroll
    for (int c = 0; c < NCHV; c++) {
        float4 x = *(const float4*)&ws[PARTV_OFF + (size_t)c * (BB * NPOS) + (size_t)b * NPOS + p0];
        ev.x += x.x; ev.y += x.y; ev.z += x.z; ev.w += x.w;
    }
    #pragma unroll
    for (int c = 0; c < NCHA; c++) {
        float4 x = *(const float4*)&ws[PARTA_OFF + (size_t)c * (BB * NPOS) + (size_t)b * NPOS + p0];
        ea.x += x.x; ea.y += x.y; ea.z += x.z; ea.w += x.w;
    }
    const float* cpt = ws + CPT_OFF;
    float4 q0 = *(const float4*)&cpt[0 * NPOS + p0];
    float4 q1 = *(const float4*)&cpt[1 * NPOS + p0];
    float4 q2 = *(const float4*)&cpt[2 * NPOS + p0];
    float4 q3 = *(const float4*)&cpt[3 * NPOS + p0];
    float4 q4 = *(const float4*)&cpt[4 * NPOS + p0];
    float4 q5 = *(const float4*)&cpt[5 * NPOS + p0];
    float4 nv = *(const float4*)&na_v[p0];
    float4 na = *(const float4*)&na_a[p0];
    float4 nm = *(const float4*)&na_m[p0];

    float evs[4] = {ev.x, ev.y, ev.z, ev.w};
    float eas[4] = {ea.x, ea.y, ea.z, ea.w};
    float nbv[4] = {q0.x + q1.x, q0.y + q1.y, q0.z + q1.z, q0.w + q1.w};
    float nba[4] = {q2.x + q3.x, q2.y + q3.y, q2.z + q3.z, q2.w + q3.w};
    float nbm[4] = {q4.x + q5.x, q4.y + q5.y, q4.z + q5.z, q4.w + q5.w};
    float nvs[4] = {nv.x, nv.y, nv.z, nv.w};
    float nas[4] = {na.x, na.y, na.z, na.w};
    float nms[4] = {nm.x, nm.y, nm.z, nm.w};

    float4 o;
    float* os = (float*)&o;
    #pragma unroll
    for (int u = 0; u < 4; u++) {
        const float xv = (evs[u] + nbv[u] - 3.0f + nms[u]) * 0.3f;
        const float nav_new = nvs[u] * (2.f / 3.f) + (1.f / 3.f) / (1.f + __expf(-xv));
        const float xa = (eas[u] + nba[u] - 3.0f + nms[u]) * 0.3f;
        const float naa_new = nas[u] * (2.f / 3.f) + (1.f / 3.f) / (1.f + __expf(-xa));
        const float xm = (7.0f * nav_new + 3.0f * naa_new + nbm[u] - 3.0f) * 0.3f;
        os[u] = nms[u] * (2.f / 3.f) + (1.f / 3.f) / (1.f + __expf(-xm));
    }
    *(float4*)&out[(size_t)b * NPOS + p0] = o;
}

extern "C" void kernel_launch(void* const* d_in, const int* in_sizes, int n_in,
                              void* d_out, int out_size, void* d_ws, size_t ws_size,
                              hipStream_t stream) {
    const float* video = (const float*)d_in[0];
    const float* audio = (const float*)d_in[1];
    const float* rf_v  = (const float*)d_in[2];
    const float* rf_a  = (const float*)d_in[3];
    const float* na_v  = (const float*)d_in[4];
    const float* na_a  = (const float*)d_in[5];
    const float* na_m  = (const float*)d_in[6];
    float* ws  = (float*)d_ws;
    float* out = (float*)d_out;

    nbT_kernel<<<72, 256, 0, stream>>>(na_v, na_a, na_m, video, audio, ws);
    ext_mfma<<<NBLK_V + NBLK_A, 64, 0, stream>>>(rf_v, rf_a, ws);
    combine_kernel<<<(BB * NPOS / 4 + 255) / 256, 256, 0, stream>>>(
        na_v, na_a, na_m, ws, out);
}